// Round 3
// baseline (460.392 us; speedup 1.0000x reference)
//
#include <hip/hip_runtime.h>
#include <hip/hip_bf16.h>

typedef __attribute__((ext_vector_type(8))) short short8;
typedef __attribute__((ext_vector_type(4))) float floatx4;
typedef unsigned int u32;

__device__ __forceinline__ u32 f2bf(float f) {
    union { float f; u32 u; } c; c.f = f;
    return (c.u + 0x7FFFu + ((c.u >> 16) & 1u)) >> 16;  // RNE
}
__device__ __forceinline__ short8 cvt8(const float* p) {
    float4 f0 = ((const float4*)p)[0];
    float4 f1 = ((const float4*)p)[1];
    short8 r;
    r[0] = (short)f2bf(f0.x); r[1] = (short)f2bf(f0.y);
    r[2] = (short)f2bf(f0.z); r[3] = (short)f2bf(f0.w);
    r[4] = (short)f2bf(f1.x); r[5] = (short)f2bf(f1.y);
    r[6] = (short)f2bf(f1.z); r[7] = (short)f2bf(f1.w);
    return r;
}

// ---- fp8 e4m3 payload helpers (HW cvt, gfx950 OCP) ----
__device__ __forceinline__ void fp8x4_acc(u32 v, float& c0, float& c1, float& c2, float& c3) {
    auto flo = __builtin_amdgcn_cvt_pk_f32_fp8((int)v, false);
    auto fhi = __builtin_amdgcn_cvt_pk_f32_fp8((int)v, true);
    c0 += ((const float*)&flo)[0];
    c1 += ((const float*)&flo)[1];
    c2 += ((const float*)&fhi)[0];
    c3 += ((const float*)&fhi)[1];
}
__device__ __forceinline__ void fp8x4_dec(u32 v, float& x0, float& x1, float& x2, float& x3) {
    auto flo = __builtin_amdgcn_cvt_pk_f32_fp8((int)v, false);
    auto fhi = __builtin_amdgcn_cvt_pk_f32_fp8((int)v, true);
    x0 = ((const float*)&flo)[0];
    x1 = ((const float*)&flo)[1];
    x2 = ((const float*)&fhi)[0];
    x3 = ((const float*)&fhi)[1];
}
__device__ __forceinline__ u32 f32x4_to_fp8(float a, float b, float c, float d) {
    u32 w = (u32)__builtin_amdgcn_cvt_pk_fp8_f32(a, b, 0, false);
    w = (u32)__builtin_amdgcn_cvt_pk_fp8_f32(c, d, (int)w, true);
    return w;
}

// Paired merged 4-node gather over fp8 rows (128 B/row = 32 dwords).
// Lane l owns feats {4*(l&31)..4*(l&31)+3}. Lanes 0-31 load row of edge 2k,
// lanes 32-63 load row of edge 2k+1 -> ONE global_load_dword per TWO edges.
// Half-wave partials are combined (shfl_xor 32) at each segment flush.
// Segment boundaries inside a pair: predicated half-adds around uniform flush.
__device__ __forceinline__ void gather4p(const u32* __restrict__ hw32,
                                         const int* __restrict__ col,
                                         int beg, int e1, int e2, int e3, int e4,
                                         int lane,
                                         float* __restrict__ A0, float* __restrict__ A1,
                                         float* __restrict__ A2, float* __restrict__ A3) {
    float c0 = 0.f, c1 = 0.f, c2 = 0.f, c3 = 0.f;
    int seg = 0, segend = e1;
    int l32 = lane & 31;
    bool lo_half = lane < 32;
#define FLUSH_SEG() do { \
        c0 += __shfl_xor(c0, 32); c1 += __shfl_xor(c1, 32); \
        c2 += __shfl_xor(c2, 32); c3 += __shfl_xor(c3, 32); \
        if (seg == 0)      { A0[0]=c0; A1[0]=c1; A2[0]=c2; A3[0]=c3; segend = e2; } \
        else if (seg == 1) { A0[1]=c0; A1[1]=c1; A2[1]=c2; A3[1]=c3; segend = e3; } \
        else if (seg == 2) { A0[2]=c0; A1[2]=c1; A2[2]=c2; A3[2]=c3; segend = e4; } \
        else if (seg == 3) { A0[3]=c0; A1[3]=c1; A2[3]=c2; A3[3]=c3; segend = 0x7fffffff; } \
        c0=c1=c2=c3=0.f; ++seg; } while (0)

#define PAIR_SLOW(vv, gb) do { \
        while ((gb) >= segend) FLUSH_SEG(); \
        if ((gb) + 1 < segend) { \
            fp8x4_acc((vv), c0, c1, c2, c3); \
        } else { \
            if (lo_half) fp8x4_acc((vv), c0, c1, c2, c3); \
            FLUSH_SEG(); \
            while ((gb) + 1 >= segend) FLUSH_SEG(); \
            if (!lo_half) fp8x4_acc((vv), c0, c1, c2, c3); \
        } } while (0)

    int idx0 = beg + lane;
    int svc = (idx0 < e4) ? col[idx0] : 0;
    for (int c = beg; c < e4; c += 64) {
        int idxn = c + 64 + lane;
        int svn = (idxn < e4) ? col[idxn] : 0;  // prefetch next col chunk
        int m = e4 - c; if (m > 64) m = 64;
        int np = (m + 1) >> 1;  // pairs in chunk (last may be a singleton)
        int pb = 0;
        for (; pb + 16 <= np; pb += 16) {
            u32 v[16];
#pragma unroll
            for (int j = 0; j < 16; ++j) {
                int jj = pb + j;
                int slo = __builtin_amdgcn_readlane(svc, 2 * jj);
                int shi = __builtin_amdgcn_readlane(svc, 2 * jj + 1);
                int r = lo_half ? slo : shi;
                v[j] = hw32[(size_t)r * 32 + l32];
            }
            int gb0 = c + 2 * pb;
            if (gb0 + 31 < segend) {
#pragma unroll
                for (int j = 0; j < 16; ++j) fp8x4_acc(v[j], c0, c1, c2, c3);
            } else {
#pragma unroll
                for (int j = 0; j < 16; ++j) PAIR_SLOW(v[j], gb0 + 2 * j);
            }
        }
        for (; pb + 4 <= np; pb += 4) {
            u32 v[4];
#pragma unroll
            for (int j = 0; j < 4; ++j) {
                int jj = pb + j;
                int slo = __builtin_amdgcn_readlane(svc, 2 * jj);
                int shi = __builtin_amdgcn_readlane(svc, 2 * jj + 1);
                int r = lo_half ? slo : shi;
                v[j] = hw32[(size_t)r * 32 + l32];
            }
            int gb0 = c + 2 * pb;
            if (gb0 + 7 < segend) {
#pragma unroll
                for (int j = 0; j < 4; ++j) fp8x4_acc(v[j], c0, c1, c2, c3);
            } else {
#pragma unroll
                for (int j = 0; j < 4; ++j) PAIR_SLOW(v[j], gb0 + 2 * j);
            }
        }
        for (; pb < np; ++pb) {
            int slo = __builtin_amdgcn_readlane(svc, 2 * pb);
            int shi = __builtin_amdgcn_readlane(svc, 2 * pb + 1);
            int r = lo_half ? slo : shi;
            u32 v = hw32[(size_t)r * 32 + l32];
            PAIR_SLOW(v, c + 2 * pb);
        }
        svc = svn;
    }
    while (seg < 4) FLUSH_SEG();
#undef PAIR_SLOW
#undef FLUSH_SEG
}

// ---------------- CSR build ----------------
__global__ __launch_bounds__(256) void hist_trans_k(
        const int* __restrict__ dst, int* __restrict__ bcnt, int E, int histB,
        const float* __restrict__ W1, const float* __restrict__ W2,
        const float* __restrict__ W3, const float* __restrict__ Wp1,
        const float* __restrict__ Wp2,
        unsigned short* __restrict__ o1, unsigned short* __restrict__ o2,
        unsigned short* __restrict__ o3, unsigned short* __restrict__ o4,
        unsigned short* __restrict__ o5) {
    int t = threadIdx.x;
    if ((int)blockIdx.x < histB) {
        __shared__ int h[512];
        h[t] = 0; h[t + 256] = 0;
        __syncthreads();
        int e0 = blockIdx.x * 4096;
        int ne = min(4096, E - e0);
        for (int i = t; i < ne; i += 256) atomicAdd(&h[dst[e0 + i] >> 8], 1);
        __syncthreads();
        int c = h[t];
        if (c) atomicAdd(&bcnt[t], c);
        c = h[t + 256];
        if (c) atomicAdd(&bcnt[t + 256], c);
    } else {
        int i = (blockIdx.x - histB) * 256 + t;
        const float* in; unsigned short* out; int cols, li;
        if (i < 16384)      { in = W1;  out = o1; cols = 128; li = i; }
        else if (i < 32768) { in = W2;  out = o2; cols = 128; li = i - 16384; }
        else if (i < 49152) { in = W3;  out = o3; cols = 128; li = i - 32768; }
        else if (i < 65536) { in = Wp1; out = o4; cols = 128; li = i - 49152; }
        else                { in = Wp2; out = o5; cols = 64;  li = i - 65536; }
        int r = li / cols, c = li - r * cols;
        out[(size_t)c * 128 + r] = (unsigned short)f2bf(in[li]);
    }
}

__global__ void bscan_k(const int* __restrict__ bcnt, int* __restrict__ bbase,
                        int* __restrict__ cursor, int nb, int E) {
    __shared__ int tmp[512];
    int t = threadIdx.x;
    int v = (t < nb) ? bcnt[t] : 0;
    tmp[t] = v;
    __syncthreads();
    for (int off = 1; off < 512; off <<= 1) {
        int a = (t >= off) ? tmp[t - off] : 0;
        __syncthreads();
        tmp[t] += a;
        __syncthreads();
    }
    if (t < nb) {
        int ex = tmp[t] - v;
        bbase[t] = ex;
        cursor[t] = ex;
    }
    if (t == 0) bbase[nb] = E;
}

__global__ __launch_bounds__(256) void bucket_k(const int* __restrict__ src,
                                                const int* __restrict__ dst,
                                                int* __restrict__ cursor,
                                                u32* __restrict__ pairs, int E, int nb) {
    __shared__ int cnt[512];
    __shared__ int gbase[512];
    __shared__ int cur[512];
    int t = threadIdx.x;
    cnt[t] = 0; cnt[t + 256] = 0;
    __syncthreads();
    int e0 = blockIdx.x * 8192;
    int ne = min(8192, E - e0);
    for (int i = t; i < ne; i += 256) atomicAdd(&cnt[dst[e0 + i] >> 8], 1);
    __syncthreads();
    for (int b = t; b < nb; b += 256) {
        int c = cnt[b];
        gbase[b] = c ? atomicAdd(&cursor[b], c) : 0;
        cur[b] = 0;
    }
    __syncthreads();
    for (int i = t; i < ne; i += 256) {
        int d = dst[e0 + i];
        int s = src[e0 + i];
        int b = d >> 8;
        int p = atomicAdd(&cur[b], 1);
        pairs[gbase[b] + p] = (u32)s | ((u32)(d & 255) << 24);
    }
}

#define LCOL_CAP 12288
__global__ __launch_bounds__(256) void build_k(const u32* __restrict__ pairs,
                                               const int* __restrict__ bbase,
                                               int* __restrict__ rowptr,
                                               float* __restrict__ dinv,
                                               int* __restrict__ col, int N, int E) {
    __shared__ int cnt[256], incl[256], cur[256];
    __shared__ int lcol[LCOL_CAP];
    int b = blockIdx.x, t = threadIdx.x;
    int base = bbase[b];
    int ecnt = bbase[b + 1] - base;
    cnt[t] = 0;
    __syncthreads();
    for (int j = t; j < ecnt; j += 256) atomicAdd(&cnt[pairs[base + j] >> 24], 1);
    __syncthreads();
    incl[t] = cnt[t];
    __syncthreads();
    for (int off = 1; off < 256; off <<= 1) {
        int a = (t >= off) ? incl[t - off] : 0;
        __syncthreads();
        incl[t] += a;
        __syncthreads();
    }
    int myc = cnt[t];
    int ex = incl[t] - myc;
    int node = b * 256 + t;
    if (node < N) {
        rowptr[node] = base + ex;
        dinv[node] = rsqrtf((float)myc + 1.0f);  // +1 self-loop
    }
    cur[t] = ex;
    if (b == 0 && t == 0) rowptr[N] = E;
    __syncthreads();
    if (ecnt <= LCOL_CAP) {
        for (int j = t; j < ecnt; j += 256) {
            u32 v = pairs[base + j];
            int r = atomicAdd(&cur[v >> 24], 1);
            lcol[r] = (int)(v & 0xFFFFFF);
        }
        __syncthreads();
        for (int j = t; j < ecnt; j += 256) col[base + j] = lcol[j];
    } else {
        for (int j = t; j < ecnt; j += 256) {
            u32 v = pairs[base + j];
            int r = atomicAdd(&cur[v >> 24], 1);
            col[base + r] = (int)(v & 0xFFFFFF);
        }
    }
}

// ---------------- GEMM (layer 1: x f32 -> hw fp8, dinv-scaled) ----------------
__global__ __launch_bounds__(256) void gemm1_k(const float* __restrict__ A,
                                               const short* __restrict__ Wt,
                                               const float* __restrict__ dinv,
                                               u32* __restrict__ out, int M) {
    int wave = threadIdx.x >> 6;
    int lane = threadIdx.x & 63;
    int m0 = blockIdx.x * 64 + wave * 16;
    if (m0 >= M) return;
    int quad = lane >> 4, lr = lane & 15;
    int row = m0 + lr;
    bool wr = row < M;
    if (row >= M) row = M - 1;
    const float* Ab = A + (size_t)row * 128 + quad * 8;
    short8 b0 = cvt8(Ab), b1 = cvt8(Ab + 32), b2 = cvt8(Ab + 64), b3 = cvt8(Ab + 96);
    float di = dinv[row];
#pragma unroll
    for (int nt = 0; nt < 8; ++nt) {
        int ncol = nt * 16 + lr;
        const short8* Wp = (const short8*)(Wt + (size_t)ncol * 128 + quad * 8);
        short8 a0 = Wp[0], a1 = Wp[4], a2 = Wp[8], a3 = Wp[12];
        floatx4 acc = {0.f, 0.f, 0.f, 0.f};
        acc = __builtin_amdgcn_mfma_f32_16x16x32_bf16(a0, b0, acc, 0, 0, 0);
        acc = __builtin_amdgcn_mfma_f32_16x16x32_bf16(a1, b1, acc, 0, 0, 0);
        acc = __builtin_amdgcn_mfma_f32_16x16x32_bf16(a2, b2, acc, 0, 0, 0);
        acc = __builtin_amdgcn_mfma_f32_16x16x32_bf16(a3, b3, acc, 0, 0, 0);
        if (wr) {
            out[(size_t)(m0 + lr) * 32 + nt * 4 + quad] =
                f32x4_to_fp8(acc[0] * di, acc[1] * di, acc[2] * di, acc[3] * di);
        }
    }
}

// ---------------- fused conv: agg(fp8 paired) + bias + relu + LN + @Wnext*dinv -> fp8 ----------------
__global__ __launch_bounds__(256) void fconv_k(const u32* __restrict__ hw32,
                                               const int* __restrict__ rowptr,
                                               const int* __restrict__ col,
                                               const float* __restrict__ dinv,
                                               const float* __restrict__ bias,
                                               const float* __restrict__ gam,
                                               const float* __restrict__ bet,
                                               const short* __restrict__ Wt,
                                               u32* __restrict__ out, int N) {
    __shared__ unsigned short rows[16][136];  // bf16 MFMA staging
    int t = threadIdx.x, wave = t >> 6, lane = t & 63;
    int l32 = lane & 31;
    int nb0 = blockIdx.x * 16;
    int node0 = nb0 + wave * 4;
    int ridx = node0 + (lane < 4 ? lane : 4);
    if (ridx > N) ridx = N;
    int rp = rowptr[ridx];
    int beg = __builtin_amdgcn_readlane(rp, 0);
    int e1  = __builtin_amdgcn_readlane(rp, 1);
    int e2  = __builtin_amdgcn_readlane(rp, 2);
    int e3  = __builtin_amdgcn_readlane(rp, 3);
    int e4  = __builtin_amdgcn_readlane(rp, 4);
    u32 selfd[4]; float dv[4];
#pragma unroll
    for (int i = 0; i < 4; ++i) {
        int node = node0 + i;
        bool ok = node < N;
        selfd[i] = ok ? hw32[(size_t)node * 32 + l32] : 0u;
        dv[i]    = ok ? dinv[node] : 0.f;
    }
    float A0[4], A1[4], A2[4], A3[4];
    gather4p(hw32, col, beg, e1, e2, e3, e4, lane, A0, A1, A2, A3);
#pragma unroll
    for (int i = 0; i < 4; ++i) {
        int r = wave * 4 + i;
        int node = node0 + i;
        float a0 = 0.f, a1 = 0.f, a2 = 0.f, a3 = 0.f;
        if (node < N) {
            float di = dv[i];
            float s0, s1, s2, s3;
            fp8x4_dec(selfd[i], s0, s1, s2, s3);
            a0 = di * (A0[i] + s0);
            a1 = di * (A1[i] + s1);
            a2 = di * (A2[i] + s2);
            a3 = di * (A3[i] + s3);
            float4 bv = *(const float4*)(bias + 4 * l32);
            a0 = fmaxf(a0 + bv.x, 0.f);
            a1 = fmaxf(a1 + bv.y, 0.f);
            a2 = fmaxf(a2 + bv.z, 0.f);
            a3 = fmaxf(a3 + bv.w, 0.f);
            float s = a0 + a1 + a2 + a3;
            float q = a0 * a0 + a1 * a1 + a2 * a2 + a3 * a3;
#pragma unroll
            for (int mm = 16; mm >= 1; mm >>= 1) {
                s += __shfl_xor(s, mm);
                q += __shfl_xor(q, mm);
            }
            float mu = s * (1.f / 128.f);
            float var = q * (1.f / 128.f) - mu * mu;
            float rs = rsqrtf(fmaxf(var, 0.f) + 1e-5f);
            float4 gv = *(const float4*)(gam + 4 * l32);
            float4 bev = *(const float4*)(bet + 4 * l32);
            a0 = gv.x * (a0 - mu) * rs + bev.x;
            a1 = gv.y * (a1 - mu) * rs + bev.y;
            a2 = gv.z * (a2 - mu) * rs + bev.z;
            a3 = gv.w * (a3 - mu) * rs + bev.w;
        }
        if (lane < 32) {
            uint2 st;
            st.x = f2bf(a0) | (f2bf(a1) << 16);
            st.y = f2bf(a2) | (f2bf(a3) << 16);
            *(uint2*)&rows[r][4 * l32] = st;
        }
    }
    __syncthreads();
    int quad = lane >> 4, lr = lane & 15;
    short8 b0 = *(const short8*)&rows[lr][quad * 8];
    short8 b1 = *(const short8*)&rows[lr][32 + quad * 8];
    short8 b2 = *(const short8*)&rows[lr][64 + quad * 8];
    short8 b3 = *(const short8*)&rows[lr][96 + quad * 8];
    int onode = nb0 + lr;
    float di2 = (onode < N) ? dinv[onode] : 0.f;
#pragma unroll
    for (int k = 0; k < 2; ++k) {
        int ct = wave * 2 + k;
        int ncol = ct * 16 + lr;
        const short8* Wp = (const short8*)(Wt + (size_t)ncol * 128 + quad * 8);
        short8 a0 = Wp[0], a1 = Wp[4], a2 = Wp[8], a3 = Wp[12];
        floatx4 acc = {0.f, 0.f, 0.f, 0.f};
        acc = __builtin_amdgcn_mfma_f32_16x16x32_bf16(a0, b0, acc, 0, 0, 0);
        acc = __builtin_amdgcn_mfma_f32_16x16x32_bf16(a1, b1, acc, 0, 0, 0);
        acc = __builtin_amdgcn_mfma_f32_16x16x32_bf16(a2, b2, acc, 0, 0, 0);
        acc = __builtin_amdgcn_mfma_f32_16x16x32_bf16(a3, b3, acc, 0, 0, 0);
        int c0 = ct * 16 + quad * 4;
        if (onode < N) {
            out[(size_t)onode * 32 + (c0 >> 2)] =
                f32x4_to_fp8(acc[0] * di2, acc[1] * di2, acc[2] * di2, acc[3] * di2);
        }
    }
}

// ---------------- fused head: agg(fp8 paired) + b3 + relu + @Wp1+bp1 + @Wp2+bp2 + sigmoid ----------------
__global__ __launch_bounds__(256) void fhead_k(const u32* __restrict__ hw32,
                                               const int* __restrict__ rowptr,
                                               const int* __restrict__ col,
                                               const float* __restrict__ dinv,
                                               const float* __restrict__ bias,
                                               const short* __restrict__ Wp1t,
                                               const float* __restrict__ bp1,
                                               const short* __restrict__ Wp2t,
                                               const float* __restrict__ bp2,
                                               float* __restrict__ out, int N) {
    __shared__ unsigned short rows[16][136];
    __shared__ unsigned short h1s[16][136];
    int t = threadIdx.x, wave = t >> 6, lane = t & 63;
    int l32 = lane & 31;
    int nb0 = blockIdx.x * 16;
    int node0 = nb0 + wave * 4;
    int ridx = node0 + (lane < 4 ? lane : 4);
    if (ridx > N) ridx = N;
    int rp = rowptr[ridx];
    int beg = __builtin_amdgcn_readlane(rp, 0);
    int e1  = __builtin_amdgcn_readlane(rp, 1);
    int e2  = __builtin_amdgcn_readlane(rp, 2);
    int e3  = __builtin_amdgcn_readlane(rp, 3);
    int e4  = __builtin_amdgcn_readlane(rp, 4);
    u32 selfd[4]; float dv[4];
#pragma unroll
    for (int i = 0; i < 4; ++i) {
        int node = node0 + i;
        bool ok = node < N;
        selfd[i] = ok ? hw32[(size_t)node * 32 + l32] : 0u;
        dv[i]    = ok ? dinv[node] : 0.f;
    }
    float A0[4], A1[4], A2[4], A3[4];
    gather4p(hw32, col, beg, e1, e2, e3, e4, lane, A0, A1, A2, A3);
#pragma unroll
    for (int i = 0; i < 4; ++i) {
        int r = wave * 4 + i;
        int node = node0 + i;
        float a0 = 0.f, a1 = 0.f, a2 = 0.f, a3 = 0.f;
        if (node < N) {
            float di = dv[i];
            float s0, s1, s2, s3;
            fp8x4_dec(selfd[i], s0, s1, s2, s3);
            a0 = di * (A0[i] + s0);
            a1 = di * (A1[i] + s1);
            a2 = di * (A2[i] + s2);
            a3 = di * (A3[i] + s3);
            float4 bv = *(const float4*)(bias + 4 * l32);
            a0 = fmaxf(a0 + bv.x, 0.f);
            a1 = fmaxf(a1 + bv.y, 0.f);
            a2 = fmaxf(a2 + bv.z, 0.f);
            a3 = fmaxf(a3 + bv.w, 0.f);
        }
        if (lane < 32) {
            uint2 st;
            st.x = f2bf(a0) | (f2bf(a1) << 16);
            st.y = f2bf(a2) | (f2bf(a3) << 16);
            *(uint2*)&rows[r][4 * l32] = st;
        }
    }
    __syncthreads();
    int quad = lane >> 4, lr = lane & 15;
    {   // h1 = h @ Wp1 + bp1  (2 col-tiles per wave)
        short8 b0 = *(const short8*)&rows[lr][quad * 8];
        short8 b1 = *(const short8*)&rows[lr][32 + quad * 8];
        short8 b2 = *(const short8*)&rows[lr][64 + quad * 8];
        short8 b3 = *(const short8*)&rows[lr][96 + quad * 8];
#pragma unroll
        for (int k = 0; k < 2; ++k) {
            int ct = wave * 2 + k;
            int ncol = ct * 16 + lr;
            const short8* Wp = (const short8*)(Wp1t + (size_t)ncol * 128 + quad * 8);
            short8 a0 = Wp[0], a1 = Wp[4], a2 = Wp[8], a3 = Wp[12];
            floatx4 acc = {0.f, 0.f, 0.f, 0.f};
            acc = __builtin_amdgcn_mfma_f32_16x16x32_bf16(a0, b0, acc, 0, 0, 0);
            acc = __builtin_amdgcn_mfma_f32_16x16x32_bf16(a1, b1, acc, 0, 0, 0);
            acc = __builtin_amdgcn_mfma_f32_16x16x32_bf16(a2, b2, acc, 0, 0, 0);
            acc = __builtin_amdgcn_mfma_f32_16x16x32_bf16(a3, b3, acc, 0, 0, 0);
            int c0 = ct * 16 + quad * 4;
            float4 bv = *(const float4*)(bp1 + c0);
            uint2 st;
            st.x = f2bf(acc[0] + bv.x) | (f2bf(acc[1] + bv.y) << 16);
            st.y = f2bf(acc[2] + bv.z) | (f2bf(acc[3] + bv.w) << 16);
            *(uint2*)&h1s[lr][c0] = st;
        }
    }
    __syncthreads();
    {   // out = sigmoid(h1 @ Wp2 + bp2)
        short8 b0 = *(const short8*)&h1s[lr][quad * 8];
        short8 b1 = *(const short8*)&h1s[lr][32 + quad * 8];
        short8 b2 = *(const short8*)&h1s[lr][64 + quad * 8];
        short8 b3 = *(const short8*)&h1s[lr][96 + quad * 8];
        int ncol = wave * 16 + lr;
        const short8* Wp = (const short8*)(Wp2t + (size_t)ncol * 128 + quad * 8);
        short8 a0 = Wp[0], a1 = Wp[4], a2 = Wp[8], a3 = Wp[12];
        floatx4 acc = {0.f, 0.f, 0.f, 0.f};
        acc = __builtin_amdgcn_mfma_f32_16x16x32_bf16(a0, b0, acc, 0, 0, 0);
        acc = __builtin_amdgcn_mfma_f32_16x16x32_bf16(a1, b1, acc, 0, 0, 0);
        acc = __builtin_amdgcn_mfma_f32_16x16x32_bf16(a2, b2, acc, 0, 0, 0);
        acc = __builtin_amdgcn_mfma_f32_16x16x32_bf16(a3, b3, acc, 0, 0, 0);
        int c0 = wave * 16 + quad * 4;
        int onode = nb0 + lr;
        if (onode < N) {
            float4 bv = *(const float4*)(bp2 + c0);
            float4 st;
            st.x = 1.f / (1.f + __expf(-(acc[0] + bv.x)));
            st.y = 1.f / (1.f + __expf(-(acc[1] + bv.y)));
            st.z = 1.f / (1.f + __expf(-(acc[2] + bv.z)));
            st.w = 1.f / (1.f + __expf(-(acc[3] + bv.w)));
            *(float4*)(out + (size_t)onode * 64 + c0) = st;
        }
    }
}

extern "C" void kernel_launch(void* const* d_in, const int* in_sizes, int n_in,
                              void* d_out, int out_size, void* d_ws, size_t ws_size,
                              hipStream_t stream) {
    const int N = in_sizes[0] / 128;
    const int E = in_sizes[1] / 2;
    const int nb = (N + 255) >> 8;
    const int* edge = (const int*)d_in[1];
    const int* srcp = edge;
    const int* dstp = edge + E;
    const float* x   = (const float*)d_in[0];
    const float* W1  = (const float*)d_in[2];
    const float* b1  = (const float*)d_in[3];
    const float* W2  = (const float*)d_in[4];
    const float* b2  = (const float*)d_in[5];
    const float* W3  = (const float*)d_in[6];
    const float* b3  = (const float*)d_in[7];
    const float* g1  = (const float*)d_in[8];
    const float* be1 = (const float*)d_in[9];
    const float* g2  = (const float*)d_in[10];
    const float* be2 = (const float*)d_in[11];
    const float* Wp1 = (const float*)d_in[12];
    const float* bp1 = (const float*)d_in[13];
    const float* Wp2 = (const float*)d_in[14];
    const float* bp2 = (const float*)d_in[15];

    char* ws = (char*)d_ws;
    size_t off = 0;
    auto alloc = [&](size_t b) -> char* {
        char* p = ws + off;
        off += (b + 255) & ~(size_t)255;
        return p;
    };
    int* bcnt   = (int*)alloc(512 * 4);
    int* bbase  = (int*)alloc((size_t)(nb + 1) * 4);
    int* cursor = (int*)alloc((size_t)nb * 4);
    int* rowptr = (int*)alloc((size_t)(N + 1) * 4);
    float* dinv = (float*)alloc((size_t)N * 4);
    u32* pairs  = (u32*)alloc((size_t)E * 4);
    int* colA   = (int*)alloc((size_t)E * 4);
    unsigned char* hw  = (unsigned char*)alloc((size_t)N * 128);  // fp8 rows
    unsigned char* hb  = (unsigned char*)alloc((size_t)N * 128);  // fp8 rows
    unsigned short* w1t = (unsigned short*)alloc(128 * 128 * 2);
    unsigned short* w2t = (unsigned short*)alloc(128 * 128 * 2);
    unsigned short* w3t = (unsigned short*)alloc(128 * 128 * 2);
    unsigned short* wp1t = (unsigned short*)alloc(128 * 128 * 2);
    unsigned short* wp2t = (unsigned short*)alloc(64 * 128 * 2);
    if (off > ws_size) return;

    int gb = (N + 63) / 64;
    int fb = (N + 15) / 16;
    int histB = (E + 4095) / 4096;

    hipMemsetAsync(bcnt, 0, 512 * 4, stream);
    hist_trans_k<<<histB + 288, 256, 0, stream>>>(dstp, bcnt, E, histB,
                                                  W1, W2, W3, Wp1, Wp2,
                                                  w1t, w2t, w3t, wp1t, wp2t);
    bscan_k<<<1, 512, 0, stream>>>(bcnt, bbase, cursor, nb, E);
    bucket_k<<<(E + 8191) / 8192, 256, 0, stream>>>(srcp, dstp, cursor, pairs, E, nb);
    build_k<<<nb, 256, 0, stream>>>(pairs, bbase, rowptr, dinv, colA, N, E);

    // K1: hw = fp8((x@W1)*dinv)
    gemm1_k<<<gb, 256, 0, stream>>>(x, (const short*)w1t, dinv, (u32*)hw, N);
    // K2: hb = fp8((LN(relu(agg(hw)+b1)) @ W2)*dinv)
    fconv_k<<<fb, 256, 0, stream>>>((const u32*)hw, rowptr, colA, dinv,
                                    b1, g1, be1, (const short*)w2t, (u32*)hb, N);
    // K3: hw = fp8((LN(relu(agg(hb)+b2)) @ W3)*dinv)
    fconv_k<<<fb, 256, 0, stream>>>((const u32*)hb, rowptr, colA, dinv,
                                    b2, g2, be2, (const short*)w3t, (u32*)hw, N);
    // K4: out = sigmoid((relu(agg(hw)+b3) @ Wp1 + bp1) @ Wp2 + bp2)
    fhead_k<<<fb, 256, 0, stream>>>((const u32*)hw, rowptr, colA, dinv, b3,
                                    (const short*)wp1t, bp1, (const short*)wp2t, bp2,
                                    (float*)d_out, N);
}

// Round 4
// 370.429 us; speedup vs baseline: 1.2429x; 1.2429x over previous
//
#include <hip/hip_runtime.h>
#include <hip/hip_bf16.h>

typedef __attribute__((ext_vector_type(8))) short short8;
typedef __attribute__((ext_vector_type(4))) float floatx4;
typedef unsigned int u32;

__device__ __forceinline__ u32 f2bf(float f) {
    union { float f; u32 u; } c; c.f = f;
    return (c.u + 0x7FFFu + ((c.u >> 16) & 1u)) >> 16;  // RNE
}
__device__ __forceinline__ short8 cvt8(const float* p) {
    float4 f0 = ((const float4*)p)[0];
    float4 f1 = ((const float4*)p)[1];
    short8 r;
    r[0] = (short)f2bf(f0.x); r[1] = (short)f2bf(f0.y);
    r[2] = (short)f2bf(f0.z); r[3] = (short)f2bf(f0.w);
    r[4] = (short)f2bf(f1.x); r[5] = (short)f2bf(f1.y);
    r[6] = (short)f2bf(f1.z); r[7] = (short)f2bf(f1.w);
    return r;
}

// ---- fp8 e4m3 helpers (HW cvt, gfx950 OCP; encode+decode use same HW) ----
__device__ __forceinline__ void fp8x8_acc(uint2 v, float* a) {
    auto f0 = __builtin_amdgcn_cvt_pk_f32_fp8((int)v.x, false);
    auto f1 = __builtin_amdgcn_cvt_pk_f32_fp8((int)v.x, true);
    auto f2 = __builtin_amdgcn_cvt_pk_f32_fp8((int)v.y, false);
    auto f3 = __builtin_amdgcn_cvt_pk_f32_fp8((int)v.y, true);
    a[0] += ((const float*)&f0)[0]; a[1] += ((const float*)&f0)[1];
    a[2] += ((const float*)&f1)[0]; a[3] += ((const float*)&f1)[1];
    a[4] += ((const float*)&f2)[0]; a[5] += ((const float*)&f2)[1];
    a[6] += ((const float*)&f3)[0]; a[7] += ((const float*)&f3)[1];
}
__device__ __forceinline__ void fp8x8_dec(uint2 v, float* x) {
    auto f0 = __builtin_amdgcn_cvt_pk_f32_fp8((int)v.x, false);
    auto f1 = __builtin_amdgcn_cvt_pk_f32_fp8((int)v.x, true);
    auto f2 = __builtin_amdgcn_cvt_pk_f32_fp8((int)v.y, false);
    auto f3 = __builtin_amdgcn_cvt_pk_f32_fp8((int)v.y, true);
    x[0] = ((const float*)&f0)[0]; x[1] = ((const float*)&f0)[1];
    x[2] = ((const float*)&f1)[0]; x[3] = ((const float*)&f1)[1];
    x[4] = ((const float*)&f2)[0]; x[5] = ((const float*)&f2)[1];
    x[6] = ((const float*)&f3)[0]; x[7] = ((const float*)&f3)[1];
}
__device__ __forceinline__ u32 f32x4_to_fp8(float a, float b, float c, float d) {
    u32 w = (u32)__builtin_amdgcn_cvt_pk_fp8_f32(a, b, 0, false);
    w = (u32)__builtin_amdgcn_cvt_pk_fp8_f32(c, d, (int)w, true);
    return w;
}

#define CCAP 264  // 256 staged cols + 8 pad (allows unclamped reads inside batch)

// Quad-per-node gather: quad q (lanes q*16..q*16+15) owns node node0+q; lane s16
// holds feats 8*s16..8*s16+7 (uint2 = 8 fp8 per row per lane). One wave-load
// serves 4 edges (one row per quad). Cols staged to LDS once, broadcast via
// same-address ds_read within quad. Accumulation per node in CSR order.
__device__ __forceinline__ void gatherq(const uint2* __restrict__ hw64,
                                        const int* __restrict__ col,
                                        int* __restrict__ ldsc,  // this wave's [CCAP]
                                        int begq, int endq, int beg, int stagelen,
                                        int lane, int s16, float* __restrict__ acc) {
    // stage merged col range [beg, beg+stagelen) (wave-cooperative)
    for (int i = lane; i < stagelen; i += 64) ldsc[i] = col[beg + i];
    __syncthreads();  // all waves stage exactly once; also orders ds_write->ds_read
    int dq = endq - begq;
    int offq = begq - beg;
    int send = min(endq, beg + stagelen);
    int sdq = max(0, send - begq);
    int mx = sdq;
    mx = max(mx, __shfl_xor(mx, 16));
    mx = max(mx, __shfl_xor(mx, 32));
    int idxcap = CCAP - 8;
    int off0 = min(offq, idxcap);  // keep ds_read in-bounds even when act=false
    for (int jb = 0; jb < mx; jb += 8) {
        uint2 v[8];
#pragma unroll
        for (int j = 0; j < 8; ++j) {
            int jj = jb + j;
            int cj = ldsc[off0 + (jj < stagelen - off0 ? jj : 0)];
            bool act = jj < sdq;
            uint2 tv; tv.x = 0u; tv.y = 0u;
            if (act) {
                cj = ldsc[offq + jj];
                tv = hw64[(size_t)cj * 16 + s16];
            }
            v[j] = tv;
        }
#pragma unroll
        for (int j = 0; j < 8; ++j) fp8x8_acc(v[j], acc);
    }
    // rare fallback: merged range exceeded staging cap
    for (int j = sdq; j < dq; ++j) {
        int cj = col[begq + j];
        uint2 tv = hw64[(size_t)cj * 16 + s16];
        fp8x8_acc(tv, acc);
    }
}

// ---------------- CSR build ----------------
__global__ __launch_bounds__(256) void hist_trans_k(
        const int* __restrict__ dst, int* __restrict__ bcnt, int E, int histB,
        const float* __restrict__ W1, const float* __restrict__ W2,
        const float* __restrict__ W3, const float* __restrict__ Wp1,
        const float* __restrict__ Wp2,
        unsigned short* __restrict__ o1, unsigned short* __restrict__ o2,
        unsigned short* __restrict__ o3, unsigned short* __restrict__ o4,
        unsigned short* __restrict__ o5) {
    int t = threadIdx.x;
    if ((int)blockIdx.x < histB) {
        __shared__ int h[512];
        h[t] = 0; h[t + 256] = 0;
        __syncthreads();
        int e0 = blockIdx.x * 4096;
        int ne = min(4096, E - e0);
        for (int i = t; i < ne; i += 256) atomicAdd(&h[dst[e0 + i] >> 8], 1);
        __syncthreads();
        int c = h[t];
        if (c) atomicAdd(&bcnt[t], c);
        c = h[t + 256];
        if (c) atomicAdd(&bcnt[t + 256], c);
    } else {
        int i = (blockIdx.x - histB) * 256 + t;
        const float* in; unsigned short* out; int cols, li;
        if (i < 16384)      { in = W1;  out = o1; cols = 128; li = i; }
        else if (i < 32768) { in = W2;  out = o2; cols = 128; li = i - 16384; }
        else if (i < 49152) { in = W3;  out = o3; cols = 128; li = i - 32768; }
        else if (i < 65536) { in = Wp1; out = o4; cols = 128; li = i - 49152; }
        else                { in = Wp2; out = o5; cols = 64;  li = i - 65536; }
        int r = li / cols, c = li - r * cols;
        out[(size_t)c * 128 + r] = (unsigned short)f2bf(in[li]);
    }
}

__global__ void bscan_k(const int* __restrict__ bcnt, int* __restrict__ bbase,
                        int* __restrict__ cursor, int nb, int E) {
    __shared__ int tmp[512];
    int t = threadIdx.x;
    int v = (t < nb) ? bcnt[t] : 0;
    tmp[t] = v;
    __syncthreads();
    for (int off = 1; off < 512; off <<= 1) {
        int a = (t >= off) ? tmp[t - off] : 0;
        __syncthreads();
        tmp[t] += a;
        __syncthreads();
    }
    if (t < nb) {
        int ex = tmp[t] - v;
        bbase[t] = ex;
        cursor[t] = ex;
    }
    if (t == 0) bbase[nb] = E;
}

__global__ __launch_bounds__(256) void bucket_k(const int* __restrict__ src,
                                                const int* __restrict__ dst,
                                                int* __restrict__ cursor,
                                                u32* __restrict__ pairs, int E, int nb) {
    __shared__ int cnt[512];
    __shared__ int gbase[512];
    __shared__ int cur[512];
    int t = threadIdx.x;
    cnt[t] = 0; cnt[t + 256] = 0;
    __syncthreads();
    int e0 = blockIdx.x * 8192;
    int ne = min(8192, E - e0);
    for (int i = t; i < ne; i += 256) atomicAdd(&cnt[dst[e0 + i] >> 8], 1);
    __syncthreads();
    for (int b = t; b < nb; b += 256) {
        int c = cnt[b];
        gbase[b] = c ? atomicAdd(&cursor[b], c) : 0;
        cur[b] = 0;
    }
    __syncthreads();
    for (int i = t; i < ne; i += 256) {
        int d = dst[e0 + i];
        int s = src[e0 + i];
        int b = d >> 8;
        int p = atomicAdd(&cur[b], 1);
        pairs[gbase[b] + p] = (u32)s | ((u32)(d & 255) << 24);
    }
}

#define LCOL_CAP 12288
__global__ __launch_bounds__(256) void build_k(const u32* __restrict__ pairs,
                                               const int* __restrict__ bbase,
                                               int* __restrict__ rowptr,
                                               float* __restrict__ dinv,
                                               int* __restrict__ col, int N, int E) {
    __shared__ int cnt[256], incl[256], cur[256];
    __shared__ int lcol[LCOL_CAP];
    int b = blockIdx.x, t = threadIdx.x;
    int base = bbase[b];
    int ecnt = bbase[b + 1] - base;
    cnt[t] = 0;
    __syncthreads();
    for (int j = t; j < ecnt; j += 256) atomicAdd(&cnt[pairs[base + j] >> 24], 1);
    __syncthreads();
    incl[t] = cnt[t];
    __syncthreads();
    for (int off = 1; off < 256; off <<= 1) {
        int a = (t >= off) ? incl[t - off] : 0;
        __syncthreads();
        incl[t] += a;
        __syncthreads();
    }
    int myc = cnt[t];
    int ex = incl[t] - myc;
    int node = b * 256 + t;
    if (node < N) {
        rowptr[node] = base + ex;
        dinv[node] = rsqrtf((float)myc + 1.0f);  // +1 self-loop
    }
    cur[t] = ex;
    if (b == 0 && t == 0) rowptr[N] = E;
    __syncthreads();
    if (ecnt <= LCOL_CAP) {
        for (int j = t; j < ecnt; j += 256) {
            u32 v = pairs[base + j];
            int r = atomicAdd(&cur[v >> 24], 1);
            lcol[r] = (int)(v & 0xFFFFFF);
        }
        __syncthreads();
        for (int j = t; j < ecnt; j += 256) col[base + j] = lcol[j];
    } else {
        for (int j = t; j < ecnt; j += 256) {
            u32 v = pairs[base + j];
            int r = atomicAdd(&cur[v >> 24], 1);
            col[base + r] = (int)(v & 0xFFFFFF);
        }
    }
}

// ---------------- GEMM (layer 1: x f32 -> hw fp8, dinv-scaled) ----------------
__global__ __launch_bounds__(256) void gemm1_k(const float* __restrict__ A,
                                               const short* __restrict__ Wt,
                                               const float* __restrict__ dinv,
                                               u32* __restrict__ out, int M) {
    int wave = threadIdx.x >> 6;
    int lane = threadIdx.x & 63;
    int m0 = blockIdx.x * 64 + wave * 16;
    if (m0 >= M) return;
    int quad = lane >> 4, lr = lane & 15;
    int row = m0 + lr;
    bool wr = row < M;
    if (row >= M) row = M - 1;
    const float* Ab = A + (size_t)row * 128 + quad * 8;
    short8 b0 = cvt8(Ab), b1 = cvt8(Ab + 32), b2 = cvt8(Ab + 64), b3 = cvt8(Ab + 96);
    float di = dinv[row];
#pragma unroll
    for (int nt = 0; nt < 8; ++nt) {
        int ncol = nt * 16 + lr;
        const short8* Wp = (const short8*)(Wt + (size_t)ncol * 128 + quad * 8);
        short8 a0 = Wp[0], a1 = Wp[4], a2 = Wp[8], a3 = Wp[12];
        floatx4 acc = {0.f, 0.f, 0.f, 0.f};
        acc = __builtin_amdgcn_mfma_f32_16x16x32_bf16(a0, b0, acc, 0, 0, 0);
        acc = __builtin_amdgcn_mfma_f32_16x16x32_bf16(a1, b1, acc, 0, 0, 0);
        acc = __builtin_amdgcn_mfma_f32_16x16x32_bf16(a2, b2, acc, 0, 0, 0);
        acc = __builtin_amdgcn_mfma_f32_16x16x32_bf16(a3, b3, acc, 0, 0, 0);
        if (wr) {
            out[(size_t)(m0 + lr) * 32 + nt * 4 + quad] =
                f32x4_to_fp8(acc[0] * di, acc[1] * di, acc[2] * di, acc[3] * di);
        }
    }
}

// ---------------- fused conv: agg(fp8 quad) + bias + relu + LN + @Wnext*dinv -> fp8 ----------------
__global__ __launch_bounds__(256) void fconv_k(const uint2* __restrict__ hw64,
                                               const int* __restrict__ rowptr,
                                               const int* __restrict__ col,
                                               const float* __restrict__ dinv,
                                               const float* __restrict__ bias,
                                               const float* __restrict__ gam,
                                               const float* __restrict__ bet,
                                               const short* __restrict__ Wt,
                                               u32* __restrict__ out, int N) {
    __shared__ unsigned short rows[16][136];
    __shared__ int ldsc[4][CCAP];
    int t = threadIdx.x, wave = t >> 6, lane = t & 63;
    int q = lane >> 4, s16 = lane & 15;
    int nb0 = blockIdx.x * 16;
    int node0 = nb0 + wave * 4;
    int node = node0 + q;
    bool ok = node < N;
    int beg = rowptr[min(node0, N)];
    int e4  = rowptr[min(node0 + 4, N)];
    int begq = rowptr[min(node, N)];
    int endq = ok ? rowptr[min(node + 1, N)] : begq;
    int stagelen = min(e4 - beg, 256);
    uint2 selfd; selfd.x = 0u; selfd.y = 0u;
    float di = 0.f;
    if (ok) {
        selfd = hw64[(size_t)node * 16 + s16];
        di = dinv[node];
    }
    float acc[8] = {0.f, 0.f, 0.f, 0.f, 0.f, 0.f, 0.f, 0.f};
    gatherq(hw64, col, ldsc[wave], begq, endq, beg, stagelen, lane, s16, acc);

    float sx[8]; fp8x8_dec(selfd, sx);
    float4 bv0 = *(const float4*)(bias + 8 * s16);
    float4 bv1 = *(const float4*)(bias + 8 * s16 + 4);
    float a[8];
    a[0] = fmaxf(di * (acc[0] + sx[0]) + bv0.x, 0.f);
    a[1] = fmaxf(di * (acc[1] + sx[1]) + bv0.y, 0.f);
    a[2] = fmaxf(di * (acc[2] + sx[2]) + bv0.z, 0.f);
    a[3] = fmaxf(di * (acc[3] + sx[3]) + bv0.w, 0.f);
    a[4] = fmaxf(di * (acc[4] + sx[4]) + bv1.x, 0.f);
    a[5] = fmaxf(di * (acc[5] + sx[5]) + bv1.y, 0.f);
    a[6] = fmaxf(di * (acc[6] + sx[6]) + bv1.z, 0.f);
    a[7] = fmaxf(di * (acc[7] + sx[7]) + bv1.w, 0.f);
    if (!ok) {
#pragma unroll
        for (int k = 0; k < 8; ++k) a[k] = 0.f;
    }
    float s = 0.f, qq = 0.f;
#pragma unroll
    for (int k = 0; k < 8; ++k) { s += a[k]; qq += a[k] * a[k]; }
#pragma unroll
    for (int mm = 8; mm >= 1; mm >>= 1) {
        s += __shfl_xor(s, mm);
        qq += __shfl_xor(qq, mm);
    }
    float mu = s * (1.f / 128.f);
    float var = qq * (1.f / 128.f) - mu * mu;
    float rs = rsqrtf(fmaxf(var, 0.f) + 1e-5f);
    float4 gv0 = *(const float4*)(gam + 8 * s16);
    float4 gv1 = *(const float4*)(gam + 8 * s16 + 4);
    float4 be0 = *(const float4*)(bet + 8 * s16);
    float4 be1 = *(const float4*)(bet + 8 * s16 + 4);
    a[0] = gv0.x * (a[0] - mu) * rs + be0.x;
    a[1] = gv0.y * (a[1] - mu) * rs + be0.y;
    a[2] = gv0.z * (a[2] - mu) * rs + be0.z;
    a[3] = gv0.w * (a[3] - mu) * rs + be0.w;
    a[4] = gv1.x * (a[4] - mu) * rs + be1.x;
    a[5] = gv1.y * (a[5] - mu) * rs + be1.y;
    a[6] = gv1.z * (a[6] - mu) * rs + be1.z;
    a[7] = gv1.w * (a[7] - mu) * rs + be1.w;
    if (!ok) {
#pragma unroll
        for (int k = 0; k < 8; ++k) a[k] = 0.f;
    }
    int r = wave * 4 + q;
    uint4 st;
    st.x = f2bf(a[0]) | (f2bf(a[1]) << 16);
    st.y = f2bf(a[2]) | (f2bf(a[3]) << 16);
    st.z = f2bf(a[4]) | (f2bf(a[5]) << 16);
    st.w = f2bf(a[6]) | (f2bf(a[7]) << 16);
    *(uint4*)((char*)&rows[r][0] + 16 * s16) = st;
    __syncthreads();

    int quad = lane >> 4, lr = lane & 15;
    short8 b0 = *(const short8*)&rows[lr][quad * 8];
    short8 b1 = *(const short8*)&rows[lr][32 + quad * 8];
    short8 b2 = *(const short8*)&rows[lr][64 + quad * 8];
    short8 b3 = *(const short8*)&rows[lr][96 + quad * 8];
    int onode = nb0 + lr;
    float di2 = (onode < N) ? dinv[onode] : 0.f;
#pragma unroll
    for (int k = 0; k < 2; ++k) {
        int ct = wave * 2 + k;
        int ncol = ct * 16 + lr;
        const short8* Wp = (const short8*)(Wt + (size_t)ncol * 128 + quad * 8);
        short8 a0 = Wp[0], a1 = Wp[4], a2 = Wp[8], a3 = Wp[12];
        floatx4 acm = {0.f, 0.f, 0.f, 0.f};
        acm = __builtin_amdgcn_mfma_f32_16x16x32_bf16(a0, b0, acm, 0, 0, 0);
        acm = __builtin_amdgcn_mfma_f32_16x16x32_bf16(a1, b1, acm, 0, 0, 0);
        acm = __builtin_amdgcn_mfma_f32_16x16x32_bf16(a2, b2, acm, 0, 0, 0);
        acm = __builtin_amdgcn_mfma_f32_16x16x32_bf16(a3, b3, acm, 0, 0, 0);
        int c0 = ct * 16 + quad * 4;
        if (onode < N) {
            out[(size_t)onode * 32 + (c0 >> 2)] =
                f32x4_to_fp8(acm[0] * di2, acm[1] * di2, acm[2] * di2, acm[3] * di2);
        }
    }
}

// ---------------- fused head: agg(fp8 quad) + b3 + relu + @Wp1+bp1 + @Wp2+bp2 + sigmoid ----------------
__global__ __launch_bounds__(256) void fhead_k(const uint2* __restrict__ hw64,
                                               const int* __restrict__ rowptr,
                                               const int* __restrict__ col,
                                               const float* __restrict__ dinv,
                                               const float* __restrict__ bias,
                                               const short* __restrict__ Wp1t,
                                               const float* __restrict__ bp1,
                                               const short* __restrict__ Wp2t,
                                               const float* __restrict__ bp2,
                                               float* __restrict__ out, int N) {
    __shared__ unsigned short rows[16][136];
    __shared__ unsigned short h1s[16][136];
    __shared__ int ldsc[4][CCAP];
    int t = threadIdx.x, wave = t >> 6, lane = t & 63;
    int q = lane >> 4, s16 = lane & 15;
    int nb0 = blockIdx.x * 16;
    int node0 = nb0 + wave * 4;
    int node = node0 + q;
    bool ok = node < N;
    int beg = rowptr[min(node0, N)];
    int e4  = rowptr[min(node0 + 4, N)];
    int begq = rowptr[min(node, N)];
    int endq = ok ? rowptr[min(node + 1, N)] : begq;
    int stagelen = min(e4 - beg, 256);
    uint2 selfd; selfd.x = 0u; selfd.y = 0u;
    float di = 0.f;
    if (ok) {
        selfd = hw64[(size_t)node * 16 + s16];
        di = dinv[node];
    }
    float acc[8] = {0.f, 0.f, 0.f, 0.f, 0.f, 0.f, 0.f, 0.f};
    gatherq(hw64, col, ldsc[wave], begq, endq, beg, stagelen, lane, s16, acc);

    float sx[8]; fp8x8_dec(selfd, sx);
    float4 bv0 = *(const float4*)(bias + 8 * s16);
    float4 bv1 = *(const float4*)(bias + 8 * s16 + 4);
    float a[8];
    a[0] = fmaxf(di * (acc[0] + sx[0]) + bv0.x, 0.f);
    a[1] = fmaxf(di * (acc[1] + sx[1]) + bv0.y, 0.f);
    a[2] = fmaxf(di * (acc[2] + sx[2]) + bv0.z, 0.f);
    a[3] = fmaxf(di * (acc[3] + sx[3]) + bv0.w, 0.f);
    a[4] = fmaxf(di * (acc[4] + sx[4]) + bv1.x, 0.f);
    a[5] = fmaxf(di * (acc[5] + sx[5]) + bv1.y, 0.f);
    a[6] = fmaxf(di * (acc[6] + sx[6]) + bv1.z, 0.f);
    a[7] = fmaxf(di * (acc[7] + sx[7]) + bv1.w, 0.f);
    if (!ok) {
#pragma unroll
        for (int k = 0; k < 8; ++k) a[k] = 0.f;
    }
    int r = wave * 4 + q;
    uint4 st;
    st.x = f2bf(a[0]) | (f2bf(a[1]) << 16);
    st.y = f2bf(a[2]) | (f2bf(a[3]) << 16);
    st.z = f2bf(a[4]) | (f2bf(a[5]) << 16);
    st.w = f2bf(a[6]) | (f2bf(a[7]) << 16);
    *(uint4*)((char*)&rows[r][0] + 16 * s16) = st;
    __syncthreads();

    int quad = lane >> 4, lr = lane & 15;
    {   // h1 = h @ Wp1 + bp1  (2 col-tiles per wave)
        short8 b0 = *(const short8*)&rows[lr][quad * 8];
        short8 b1 = *(const short8*)&rows[lr][32 + quad * 8];
        short8 b2 = *(const short8*)&rows[lr][64 + quad * 8];
        short8 b3 = *(const short8*)&rows[lr][96 + quad * 8];
#pragma unroll
        for (int k = 0; k < 2; ++k) {
            int ct = wave * 2 + k;
            int ncol = ct * 16 + lr;
            const short8* Wp = (const short8*)(Wp1t + (size_t)ncol * 128 + quad * 8);
            short8 a0 = Wp[0], a1 = Wp[4], a2 = Wp[8], a3 = Wp[12];
            floatx4 acm = {0.f, 0.f, 0.f, 0.f};
            acm = __builtin_amdgcn_mfma_f32_16x16x32_bf16(a0, b0, acm, 0, 0, 0);
            acm = __builtin_amdgcn_mfma_f32_16x16x32_bf16(a1, b1, acm, 0, 0, 0);
            acm = __builtin_amdgcn_mfma_f32_16x16x32_bf16(a2, b2, acm, 0, 0, 0);
            acm = __builtin_amdgcn_mfma_f32_16x16x32_bf16(a3, b3, acm, 0, 0, 0);
            int c0 = ct * 16 + quad * 4;
            float4 bv = *(const float4*)(bp1 + c0);
            uint2 stq;
            stq.x = f2bf(acm[0] + bv.x) | (f2bf(acm[1] + bv.y) << 16);
            stq.y = f2bf(acm[2] + bv.z) | (f2bf(acm[3] + bv.w) << 16);
            *(uint2*)&h1s[lr][c0] = stq;
        }
    }
    __syncthreads();
    {   // out = sigmoid(h1 @ Wp2 + bp2)
        short8 b0 = *(const short8*)&h1s[lr][quad * 8];
        short8 b1 = *(const short8*)&h1s[lr][32 + quad * 8];
        short8 b2 = *(const short8*)&h1s[lr][64 + quad * 8];
        short8 b3 = *(const short8*)&h1s[lr][96 + quad * 8];
        int ncol = wave * 16 + lr;
        const short8* Wp = (const short8*)(Wp2t + (size_t)ncol * 128 + quad * 8);
        short8 a0 = Wp[0], a1 = Wp[4], a2 = Wp[8], a3 = Wp[12];
        floatx4 acm = {0.f, 0.f, 0.f, 0.f};
        acm = __builtin_amdgcn_mfma_f32_16x16x32_bf16(a0, b0, acm, 0, 0, 0);
        acm = __builtin_amdgcn_mfma_f32_16x16x32_bf16(a1, b1, acm, 0, 0, 0);
        acm = __builtin_amdgcn_mfma_f32_16x16x32_bf16(a2, b2, acm, 0, 0, 0);
        acm = __builtin_amdgcn_mfma_f32_16x16x32_bf16(a3, b3, acm, 0, 0, 0);
        int c0 = wave * 16 + quad * 4;
        int onode = nb0 + lr;
        if (onode < N) {
            float4 bv = *(const float4*)(bp2 + c0);
            float4 sg;
            sg.x = 1.f / (1.f + __expf(-(acm[0] + bv.x)));
            sg.y = 1.f / (1.f + __expf(-(acm[1] + bv.y)));
            sg.z = 1.f / (1.f + __expf(-(acm[2] + bv.z)));
            sg.w = 1.f / (1.f + __expf(-(acm[3] + bv.w)));
            *(float4*)(out + (size_t)onode * 64 + c0) = sg;
        }
    }
}

extern "C" void kernel_launch(void* const* d_in, const int* in_sizes, int n_in,
                              void* d_out, int out_size, void* d_ws, size_t ws_size,
                              hipStream_t stream) {
    const int N = in_sizes[0] / 128;
    const int E = in_sizes[1] / 2;
    const int nb = (N + 255) >> 8;
    const int* edge = (const int*)d_in[1];
    const int* srcp = edge;
    const int* dstp = edge + E;
    const float* x   = (const float*)d_in[0];
    const float* W1  = (const float*)d_in[2];
    const float* b1  = (const float*)d_in[3];
    const float* W2  = (const float*)d_in[4];
    const float* b2  = (const float*)d_in[5];
    const float* W3  = (const float*)d_in[6];
    const float* b3  = (const float*)d_in[7];
    const float* g1  = (const float*)d_in[8];
    const float* be1 = (const float*)d_in[9];
    const float* g2  = (const float*)d_in[10];
    const float* be2 = (const float*)d_in[11];
    const float* Wp1 = (const float*)d_in[12];
    const float* bp1 = (const float*)d_in[13];
    const float* Wp2 = (const float*)d_in[14];
    const float* bp2 = (const float*)d_in[15];

    char* ws = (char*)d_ws;
    size_t off = 0;
    auto alloc = [&](size_t b) -> char* {
        char* p = ws + off;
        off += (b + 255) & ~(size_t)255;
        return p;
    };
    int* bcnt   = (int*)alloc(512 * 4);
    int* bbase  = (int*)alloc((size_t)(nb + 1) * 4);
    int* cursor = (int*)alloc((size_t)nb * 4);
    int* rowptr = (int*)alloc((size_t)(N + 1) * 4);
    float* dinv = (float*)alloc((size_t)N * 4);
    u32* pairs  = (u32*)alloc((size_t)E * 4);
    int* colA   = (int*)alloc((size_t)E * 4);
    unsigned char* hw  = (unsigned char*)alloc((size_t)N * 128);  // fp8 rows
    unsigned char* hb  = (unsigned char*)alloc((size_t)N * 128);  // fp8 rows
    unsigned short* w1t = (unsigned short*)alloc(128 * 128 * 2);
    unsigned short* w2t = (unsigned short*)alloc(128 * 128 * 2);
    unsigned short* w3t = (unsigned short*)alloc(128 * 128 * 2);
    unsigned short* wp1t = (unsigned short*)alloc(128 * 128 * 2);
    unsigned short* wp2t = (unsigned short*)alloc(64 * 128 * 2);
    if (off > ws_size) return;

    int gb = (N + 63) / 64;
    int fb = (N + 15) / 16;
    int histB = (E + 4095) / 4096;

    hipMemsetAsync(bcnt, 0, 512 * 4, stream);
    hist_trans_k<<<histB + 288, 256, 0, stream>>>(dstp, bcnt, E, histB,
                                                  W1, W2, W3, Wp1, Wp2,
                                                  w1t, w2t, w3t, wp1t, wp2t);
    bscan_k<<<1, 512, 0, stream>>>(bcnt, bbase, cursor, nb, E);
    bucket_k<<<(E + 8191) / 8192, 256, 0, stream>>>(srcp, dstp, cursor, pairs, E, nb);
    build_k<<<nb, 256, 0, stream>>>(pairs, bbase, rowptr, dinv, colA, N, E);

    // K1: hw = fp8((x@W1)*dinv)
    gemm1_k<<<gb, 256, 0, stream>>>(x, (const short*)w1t, dinv, (u32*)hw, N);
    // K2: hb = fp8((LN(relu(agg(hw)+b1)) @ W2)*dinv)
    fconv_k<<<fb, 256, 0, stream>>>((const uint2*)hw, rowptr, colA, dinv,
                                    b1, g1, be1, (const short*)w2t, (u32*)hb, N);
    // K3: hw = fp8((LN(relu(agg(hb)+b2)) @ W3)*dinv)
    fconv_k<<<fb, 256, 0, stream>>>((const uint2*)hb, rowptr, colA, dinv,
                                    b2, g2, be2, (const short*)w3t, (u32*)hw, N);
    // K4: out = sigmoid((relu(agg(hw)+b3) @ Wp1 + bp1) @ Wp2 + bp2)
    fhead_k<<<fb, 256, 0, stream>>>((const uint2*)hw, rowptr, colA, dinv, b3,
                                    (const short*)wp1t, bp1, (const short*)wp2t, bp2,
                                    (float*)d_out, N);
}